// Round 7
// baseline (169.418 us; speedup 1.0000x reference)
//
#include <hip/hip_runtime.h>
#include <hip/hip_bf16.h>

// Problem constants
#define BDIM 8
#define NNODE 2048
#define CIN 256
#define NEDGE 32768
#define NHEAD 8
#define COUT 64
#define HC 512            // NHEAD * COUT
#define BN_TOT 16384      // BDIM * NNODE
#define NEG_SLOPE 0.2f

typedef __hip_bfloat16 bf16;
typedef __attribute__((ext_vector_type(8))) short bfrag;   // 8 bf16 = 4 VGPRs
typedef __attribute__((ext_vector_type(4))) float ffrag;   // 4 fp32 acc

static __device__ __forceinline__ short f2b(float f) {
    __hip_bfloat16 h = __float2bfloat16(f);
    return *(short*)&h;
}
static __device__ __forceinline__ float b2f(short s) {
    return __uint_as_float(((unsigned)(unsigned short)s) << 16);
}

// ---------------------------------------------------------------------------
// Kernel 1 (fused prep): blocks 0..127 transpose W -> WT bf16 [512][256];
// blocks 128..2175 convert x -> xbf; block 2176 builds the CSR histogram +
// scan entirely in LDS (E=32K edges over 2048 counters) and writes
// cnt / rowptr0 / widx. No global memset, no separate count/scan dispatches;
// CSR prep overlaps the conversion blocks.
// ---------------------------------------------------------------------------
__global__ __launch_bounds__(256) void prep_kernel(const float* __restrict__ x,
                                                   const float* __restrict__ W,
                                                   const int* __restrict__ ei,
                                                   short* __restrict__ xbf,
                                                   short* __restrict__ WT,
                                                   int* __restrict__ cnt,
                                                   int* __restrict__ rowptr0,
                                                   int* __restrict__ widx) {
    const int b = blockIdx.x;
    if (b < 128) {
        __shared__ float t[32][33];
        const int kt = b >> 4;
        const int nt = b & 15;
        const int tx = threadIdx.x & 31, ty = threadIdx.x >> 5;
#pragma unroll
        for (int i = 0; i < 4; ++i)
            t[ty + 8 * i][tx] = W[(kt * 32 + ty + 8 * i) * HC + nt * 32 + tx];
        __syncthreads();
#pragma unroll
        for (int i = 0; i < 4; ++i)
            WT[(nt * 32 + ty + 8 * i) * CIN + kt * 32 + tx] = f2b(t[tx][ty + 8 * i]);
    } else if (b < 2176) {
        const int t = (b - 128) * 256 + threadIdx.x;
        const float4* px = (const float4*)x;
        float4 v0 = px[t * 2], v1 = px[t * 2 + 1];
        bfrag o;
        o[0] = f2b(v0.x); o[1] = f2b(v0.y); o[2] = f2b(v0.z); o[3] = f2b(v0.w);
        o[4] = f2b(v1.x); o[5] = f2b(v1.y); o[6] = f2b(v1.z); o[7] = f2b(v1.w);
        *(bfrag*)&xbf[t * 8] = o;
    } else {
        // single block: LDS histogram over dst + exclusive scan + cursor init
        __shared__ int hcnt[NNODE];
        __shared__ int sums[256];
        const int t = threadIdx.x;
        for (int k = t; k < NNODE; k += 256) hcnt[k] = 0;
        __syncthreads();
        const int* dst = ei + NEDGE;
        for (int e = t; e < NEDGE; e += 256) atomicAdd(&hcnt[dst[e]], 1);
        __syncthreads();
        int v[8];
        int tot = 0;
#pragma unroll
        for (int i = 0; i < 8; ++i) { v[i] = hcnt[t * 8 + i]; tot += v[i]; }
        sums[t] = tot;
        __syncthreads();
        for (int off = 1; off < 256; off <<= 1) {
            int xv = (t >= off) ? sums[t - off] : 0;
            __syncthreads();
            sums[t] += xv;
            __syncthreads();
        }
        int run = sums[t] - tot;
        int base[8];
#pragma unroll
        for (int i = 0; i < 8; ++i) { base[i] = run; run += v[i]; }
#pragma unroll
        for (int i = 0; i < 8; ++i) {
            const int n = t * 8 + i;
            cnt[n] = v[i];
            rowptr0[n] = base[i];
        }
#pragma unroll
        for (int b2 = 0; b2 < BDIM; ++b2)
#pragma unroll
            for (int i = 0; i < 8; ++i)
                widx[b2 * NNODE + t * 8 + i] = b2 * NEDGE + base[i];
    }
}

// ---------------------------------------------------------------------------
// Kernel 2 (fused): blocks 0..511 = bf16 MFMA GEMM (xtb = xbf @ WT^T);
// blocks 512..1535 = edge scatter into CSR (independent work, overlapped).
// GEMM: 128x128 tile, BK=32, 4 waves x 64x64 quadrant, bf16 output.
// ---------------------------------------------------------------------------
__global__ __launch_bounds__(256) void gemm_scatter(const short* __restrict__ xbf,
                                                    const short* __restrict__ WT,
                                                    short* __restrict__ xtb,
                                                    const int* __restrict__ ei,
                                                    int* __restrict__ widx,
                                                    int* __restrict__ col) {
    const int blk = blockIdx.x;
    if (blk >= 512) {
        const int t = (blk - 512) * 256 + threadIdx.x;   // 0..262143
        const int b = t >> 15;
        const int e = t & (NEDGE - 1);
        const int s = ei[e];
        const int d = ei[NEDGE + e];
        const int p = atomicAdd(&widx[b * NNODE + d], 1);
        col[p] = b * NNODE + s;
        return;
    }

    __shared__ __align__(16) short As[128][40];
    __shared__ __align__(16) short Bs[128][40];

    const int tid  = threadIdx.x;
    const int row0 = (blk >> 2) * 128;
    const int col0 = (blk & 3) * 128;
    const int w    = tid >> 6;
    const int lane = tid & 63;
    const int wm   = (w & 1) * 64;
    const int wn   = (w >> 1) * 64;
    const int fm   = lane & 15;
    const int fq   = lane >> 4;

    const int sr = tid >> 2;
    const int sc = (tid & 3) * 8;

    ffrag acc[4][4] = {};

    for (int k0 = 0; k0 < CIN; k0 += 32) {
        bfrag a0 = *(const bfrag*)&xbf[(row0 + sr) * CIN + k0 + sc];
        bfrag a1 = *(const bfrag*)&xbf[(row0 + sr + 64) * CIN + k0 + sc];
        bfrag b0 = *(const bfrag*)&WT[(col0 + sr) * CIN + k0 + sc];
        bfrag b1 = *(const bfrag*)&WT[(col0 + sr + 64) * CIN + k0 + sc];
        __syncthreads();
        *(bfrag*)&As[sr][sc]      = a0;
        *(bfrag*)&As[sr + 64][sc] = a1;
        *(bfrag*)&Bs[sr][sc]      = b0;
        *(bfrag*)&Bs[sr + 64][sc] = b1;
        __syncthreads();

        bfrag af[4], bfr[4];
#pragma unroll
        for (int g = 0; g < 4; ++g) {
            af[g]  = *(const bfrag*)&As[wm + g * 16 + fm][fq * 8];
            bfr[g] = *(const bfrag*)&Bs[wn + g * 16 + fm][fq * 8];
        }
#pragma unroll
        for (int mg = 0; mg < 4; ++mg)
#pragma unroll
            for (int ng = 0; ng < 4; ++ng)
                acc[mg][ng] = __builtin_amdgcn_mfma_f32_16x16x32_bf16(
                    af[mg], bfr[ng], acc[mg][ng], 0, 0, 0);
    }

#pragma unroll
    for (int mg = 0; mg < 4; ++mg)
#pragma unroll
        for (int ng = 0; ng < 4; ++ng) {
            const int rbase = row0 + wm + mg * 16 + fq * 4;
            const int c     = col0 + wn + ng * 16 + fm;
#pragma unroll
            for (int r = 0; r < 4; ++r)
                xtb[(rbase + r) * HC + c] = f2b(acc[mg][ng][r]);
        }
}

// ---------------------------------------------------------------------------
// Kernel 3: per-node attention scores, reading bf16 xtb (unchanged).
// ---------------------------------------------------------------------------
__global__ __launch_bounds__(256) void att_scores(const short* __restrict__ xtb,
                                                  const float* __restrict__ att_src,
                                                  const float* __restrict__ att_dst,
                                                  float* __restrict__ ssrc,
                                                  float* __restrict__ sdst) {
    const int n = blockIdx.x * 4 + (threadIdx.x >> 6);
    const int l = threadIdx.x & 63;

    bfrag xv = *(const bfrag*)&xtb[n * HC + l * 8];
    const float4* as = (const float4*)&att_src[l * 8];
    float4 a0 = as[0], a1 = as[1];
    const float4* ad = (const float4*)&att_dst[l * 8];
    float4 b0 = ad[0], b1 = ad[1];

    float xf[8];
#pragma unroll
    for (int k = 0; k < 8; ++k) xf[k] = b2f(xv[k]);

    float ps = xf[0] * a0.x + xf[1] * a0.y + xf[2] * a0.z + xf[3] * a0.w +
               xf[4] * a1.x + xf[5] * a1.y + xf[6] * a1.z + xf[7] * a1.w;
    float pd = xf[0] * b0.x + xf[1] * b0.y + xf[2] * b0.z + xf[3] * b0.w +
               xf[4] * b1.x + xf[5] * b1.y + xf[6] * b1.z + xf[7] * b1.w;

    ps += __shfl_xor(ps, 4); ps += __shfl_xor(ps, 2); ps += __shfl_xor(ps, 1);
    pd += __shfl_xor(pd, 4); pd += __shfl_xor(pd, 2); pd += __shfl_xor(pd, 1);

    if ((l & 7) == 0) {
        ssrc[n * NHEAD + (l >> 3)] = ps;
        sdst[n * NHEAD + (l >> 3)] = pd;
    }
}

// ---------------------------------------------------------------------------
// Kernel 4: merged-head aggregation, bf16 gather + batch->XCD swizzle.
//   Pass A stashes source ids in wave-private LDS (jlds) so phase 3 has NO
//   col[] dependency: per 8-edge group it does 2 ds_read_b128 (w) +
//   2 ds_read int4 (j) + 8 independent 16B global gathers -> deep MLP.
//   Pad slots: j=i (valid), w=0 (pre-zeroed) -> no clamps.
// ---------------------------------------------------------------------------
__global__ __launch_bounds__(256) void aggregate(const short* __restrict__ xtb,
                                                 const float* __restrict__ ssrc,
                                                 const float* __restrict__ sdst,
                                                 const int* __restrict__ cnt,
                                                 const int* __restrict__ rowptr0,
                                                 const int* __restrict__ col,
                                                 const float* __restrict__ bias,
                                                 float* __restrict__ out) {
    __shared__ float wlds[4][NHEAD][68];
    __shared__ int   jlds[4][64];
    const int nb   = threadIdx.x >> 6;
    const int lane = threadIdx.x & 63;
    const int blk  = blockIdx.x;
    const int bidx = blk & 7;                                   // batch -> XCD
    const int i    = bidx * NNODE + (blk >> 3) * 4 + nb;
    const int n    = i & (NNODE - 1);
    const int deg  = cnt[n];
    const int start = bidx * NEDGE + rowptr0[n];
    const int h    = lane >> 3;
    const int sub  = lane & 7;
    float* wrow = &wlds[nb][0][0];
    int*   jrow = &jlds[nb][0];

    for (int t = lane; t < NHEAD * 68; t += 64) wrow[t] = 0.f;
    jrow[lane] = i;

    const float sdh = sdst[i * NHEAD + h];
    float selfv = ssrc[i * NHEAD + h] + sdh;
    selfv = selfv >= 0.f ? selfv : NEG_SLOPE * selfv;

    // pass A: logits -> LDS, source ids -> LDS, running max
    float m = selfv;
    for (int e = sub; e < deg; e += 8) {
        int j = col[start + e];
        float v = ssrc[j * NHEAD + h] + sdh;
        v = v >= 0.f ? v : NEG_SLOPE * v;
        if (e < 64) {
            wrow[h * 68 + e] = v;
            if (h == 0) jrow[e] = j;
        }
        m = fmaxf(m, v);
    }
    m = fmaxf(m, __shfl_xor(m, 4));
    m = fmaxf(m, __shfl_xor(m, 2));
    m = fmaxf(m, __shfl_xor(m, 1));

    // pass B: exp, sum; overwrite LDS with unnormalized weights
    float sp = 0.f;
    for (int e = sub; e < deg; e += 8) {
        float v;
        if (e < 64) {
            v = wrow[h * 68 + e];
        } else {
            int j = col[start + e];
            v = ssrc[j * NHEAD + h] + sdh;
            v = v >= 0.f ? v : NEG_SLOPE * v;
        }
        float w = __expf(v - m);
        if (e < 64) wrow[h * 68 + e] = w;
        sp += w;
    }
    sp += __shfl_xor(sp, 4); sp += __shfl_xor(sp, 2); sp += __shfl_xor(sp, 1);
    const float eself = __expf(selfv - m);
    const float inv = 1.f / (sp + eself + 1e-16f);
    // m, sp, inv, eself, sdh uniform per 8-lane group == per-head values for
    // head h = lane>>3, exactly the head lane l owns in phase 3.

    const int c8 = lane * 8;
    float acc[8] = {};

    // self-loop
    {
        bfrag xv = *(const bfrag*)&xtb[i * HC + c8];
#pragma unroll
        for (int k = 0; k < 8; ++k) acc[k] += eself * b2f(xv[k]);
    }

    const int degc = min(deg, 64);
    const int degp = (degc + 7) & ~7;
    for (int e0 = 0; e0 < degp; e0 += 8) {
        float4 wA = *(const float4*)&wrow[h * 68 + e0];
        float4 wB = *(const float4*)&wrow[h * 68 + e0 + 4];
        int4 jA = *(const int4*)&jrow[e0];
        int4 jB = *(const int4*)&jrow[e0 + 4];
        bfrag x0 = *(const bfrag*)&xtb[jA.x * HC + c8];
        bfrag x1 = *(const bfrag*)&xtb[jA.y * HC + c8];
        bfrag x2 = *(const bfrag*)&xtb[jA.z * HC + c8];
        bfrag x3 = *(const bfrag*)&xtb[jA.w * HC + c8];
        bfrag x4 = *(const bfrag*)&xtb[jB.x * HC + c8];
        bfrag x5 = *(const bfrag*)&xtb[jB.y * HC + c8];
        bfrag x6 = *(const bfrag*)&xtb[jB.z * HC + c8];
        bfrag x7 = *(const bfrag*)&xtb[jB.w * HC + c8];
#pragma unroll
        for (int k = 0; k < 8; ++k) {
            acc[k] += wA.x * b2f(x0[k]) + wA.y * b2f(x1[k]) +
                      wA.z * b2f(x2[k]) + wA.w * b2f(x3[k]) +
                      wB.x * b2f(x4[k]) + wB.y * b2f(x5[k]) +
                      wB.z * b2f(x6[k]) + wB.w * b2f(x7[k]);
        }
    }
    // correctness fallback for deg > 64
    for (int e = 64; e < deg; ++e) {
        int j = col[start + e];
        float v = ssrc[j * NHEAD + h] + sdh;
        v = v >= 0.f ? v : NEG_SLOPE * v;
        float wv = __expf(v - m);
        bfrag xv = *(const bfrag*)&xtb[j * HC + c8];
#pragma unroll
        for (int k = 0; k < 8; ++k) acc[k] += wv * b2f(xv[k]);
    }

    const float4 b0 = *(const float4*)&bias[c8];
    const float4 b1 = *(const float4*)&bias[c8 + 4];
    float4 o0 = {acc[0] * inv + b0.x, acc[1] * inv + b0.y,
                 acc[2] * inv + b0.z, acc[3] * inv + b0.w};
    float4 o1 = {acc[4] * inv + b1.x, acc[5] * inv + b1.y,
                 acc[6] * inv + b1.z, acc[7] * inv + b1.w};
    *(float4*)&out[i * HC + c8]     = o0;
    *(float4*)&out[i * HC + c8 + 4] = o1;
}

// ---------------------------------------------------------------------------
extern "C" void kernel_launch(void* const* d_in, const int* in_sizes, int n_in,
                              void* d_out, int out_size, void* d_ws, size_t ws_size,
                              hipStream_t stream) {
    const float* x       = (const float*)d_in[0];
    const int*   ei      = (const int*)d_in[1];
    const float* W       = (const float*)d_in[2];
    const float* att_src = (const float*)d_in[3];
    const float* att_dst = (const float*)d_in[4];
    const float* bias    = (const float*)d_in[5];
    float* out = (float*)d_out;

    char* ws = (char*)d_ws;
    short* xtb     = (short*)(ws);                                 // 16777216 B
    float* ssrc    = (float*)(ws + 16777216);                      // 524288 B
    float* sdst    = (float*)(ws + 17301504);                      // 524288 B
    int*   cnt     = (int*)(ws + 17825792);                        // 8192 B
    int*   rowptr0 = (int*)(ws + 17833984);                        // 8192 B
    int*   widx    = (int*)(ws + 17842176);                        // 65536 B
    int*   col     = (int*)(ws + 17907712);                        // 1048576 B
    short* xbf     = (short*)(ws + 18956288);                      // 8388608 B
    short* WT      = (short*)(ws + 27344896);                      // 262144 B
                                                                   // total 27607040 B
    prep_kernel<<<2177, 256, 0, stream>>>(x, W, ei, xbf, WT, cnt, rowptr0, widx);
    gemm_scatter<<<1536, 256, 0, stream>>>(xbf, WT, xtb, ei, widx, col);
    att_scores<<<BN_TOT / 4, 256, 0, stream>>>(xtb, att_src, att_dst, ssrc, sdst);
    aggregate<<<BN_TOT / 4, 256, 0, stream>>>(xtb, ssrc, sdst, cnt, rowptr0, col, bias, out);
}

// Round 8
// 151.299 us; speedup vs baseline: 1.1198x; 1.1198x over previous
//
#include <hip/hip_runtime.h>
#include <hip/hip_bf16.h>

// Problem constants
#define BDIM 8
#define NNODE 2048
#define CIN 256
#define NEDGE 32768
#define NHEAD 8
#define COUT 64
#define HC 512            // NHEAD * COUT
#define BN_TOT 16384      // BDIM * NNODE
#define NEG_SLOPE 0.2f
#define NHIST 32          // partial-histogram blocks

typedef __hip_bfloat16 bf16;
typedef __attribute__((ext_vector_type(8))) short bfrag;   // 8 bf16 = 4 VGPRs
typedef __attribute__((ext_vector_type(4))) float ffrag;   // 4 fp32 acc

static __device__ __forceinline__ short f2b(float f) {
    __hip_bfloat16 h = __float2bfloat16(f);
    return *(short*)&h;
}
static __device__ __forceinline__ float b2f(short s) {
    return __uint_as_float(((unsigned)(unsigned short)s) << 16);
}

// ---------------------------------------------------------------------------
// Kernel 1 (fused prep):
//   blocks 0..127    : transpose W -> WT bf16 [512][256]
//   blocks 128..2175 : convert x -> xbf
//   blocks 2176..2207: PARTIAL histograms — block p owns edges [p*1024,
//                      (p+1)*1024): LDS histogram, then writes its private
//                      column cnt_part[n][p]. No atomics on global, no
//                      serial straggler (round-7 lesson: one block doing all
//                      32K edges serialized the whole dispatch at 60 µs).
// ---------------------------------------------------------------------------
__global__ __launch_bounds__(256) void prep_kernel(const float* __restrict__ x,
                                                   const float* __restrict__ W,
                                                   const int* __restrict__ ei,
                                                   short* __restrict__ xbf,
                                                   short* __restrict__ WT,
                                                   int* __restrict__ cnt_part) {
    const int b = blockIdx.x;
    if (b < 128) {
        __shared__ float t[32][33];
        const int kt = b >> 4;
        const int nt = b & 15;
        const int tx = threadIdx.x & 31, ty = threadIdx.x >> 5;
#pragma unroll
        for (int i = 0; i < 4; ++i)
            t[ty + 8 * i][tx] = W[(kt * 32 + ty + 8 * i) * HC + nt * 32 + tx];
        __syncthreads();
#pragma unroll
        for (int i = 0; i < 4; ++i)
            WT[(nt * 32 + ty + 8 * i) * CIN + kt * 32 + tx] = f2b(t[tx][ty + 8 * i]);
    } else if (b < 2176) {
        const int t = (b - 128) * 256 + threadIdx.x;
        const float4* px = (const float4*)x;
        float4 v0 = px[t * 2], v1 = px[t * 2 + 1];
        bfrag o;
        o[0] = f2b(v0.x); o[1] = f2b(v0.y); o[2] = f2b(v0.z); o[3] = f2b(v0.w);
        o[4] = f2b(v1.x); o[5] = f2b(v1.y); o[6] = f2b(v1.z); o[7] = f2b(v1.w);
        *(bfrag*)&xbf[t * 8] = o;
    } else {
        __shared__ int hcnt[NNODE];
        const int p = b - 2176;
        const int t = threadIdx.x;
        for (int k = t; k < NNODE; k += 256) hcnt[k] = 0;
        __syncthreads();
        const int* dst = ei + NEDGE;
        const int base = p * (NEDGE / NHIST);
#pragma unroll
        for (int k = 0; k < NEDGE / NHIST / 256; ++k)
            atomicAdd(&hcnt[dst[base + t + k * 256]], 1);
        __syncthreads();
        for (int k = t; k < NNODE; k += 256) cnt_part[k * NHIST + p] = hcnt[k];
    }
}

// ---------------------------------------------------------------------------
// Kernel 2: single-block CSR finalize — sum 32 partials per node (int4
// loads), exclusive scan over 2048 nodes, write cnt / rowptr0 / widx.
// ~256 KB of reads; a few microseconds.
// ---------------------------------------------------------------------------
__global__ __launch_bounds__(256) void scan_kernel(const int* __restrict__ cnt_part,
                                                   int* __restrict__ cnt,
                                                   int* __restrict__ rowptr0,
                                                   int* __restrict__ widx) {
    __shared__ int sums[256];
    const int t = threadIdx.x;
    int v[8];
    int tot = 0;
#pragma unroll
    for (int i = 0; i < 8; ++i) {
        const int n = t * 8 + i;
        int s = 0;
#pragma unroll
        for (int p4 = 0; p4 < NHIST; p4 += 4) {
            int4 c = *(const int4*)&cnt_part[n * NHIST + p4];
            s += c.x + c.y + c.z + c.w;
        }
        v[i] = s;
        tot += s;
    }
    sums[t] = tot;
    __syncthreads();
    for (int off = 1; off < 256; off <<= 1) {
        int xv = (t >= off) ? sums[t - off] : 0;
        __syncthreads();
        sums[t] += xv;
        __syncthreads();
    }
    int run = sums[t] - tot;
    int base[8];
#pragma unroll
    for (int i = 0; i < 8; ++i) { base[i] = run; run += v[i]; }
#pragma unroll
    for (int i = 0; i < 8; ++i) {
        const int n = t * 8 + i;
        cnt[n] = v[i];
        rowptr0[n] = base[i];
    }
#pragma unroll
    for (int b2 = 0; b2 < BDIM; ++b2)
#pragma unroll
        for (int i = 0; i < 8; ++i)
            widx[b2 * NNODE + t * 8 + i] = b2 * NEDGE + base[i];
}

// ---------------------------------------------------------------------------
// Kernel 3 (fused): blocks 0..511 = bf16 MFMA GEMM (xtb = xbf @ WT^T);
// blocks 512..1535 = edge scatter into CSR (independent, overlapped).
// ---------------------------------------------------------------------------
__global__ __launch_bounds__(256) void gemm_scatter(const short* __restrict__ xbf,
                                                    const short* __restrict__ WT,
                                                    short* __restrict__ xtb,
                                                    const int* __restrict__ ei,
                                                    int* __restrict__ widx,
                                                    int* __restrict__ col) {
    const int blk = blockIdx.x;
    if (blk >= 512) {
        const int t = (blk - 512) * 256 + threadIdx.x;   // 0..262143
        const int b = t >> 15;
        const int e = t & (NEDGE - 1);
        const int s = ei[e];
        const int d = ei[NEDGE + e];
        const int p = atomicAdd(&widx[b * NNODE + d], 1);
        col[p] = b * NNODE + s;
        return;
    }

    __shared__ __align__(16) short As[128][40];
    __shared__ __align__(16) short Bs[128][40];

    const int tid  = threadIdx.x;
    const int row0 = (blk >> 2) * 128;
    const int col0 = (blk & 3) * 128;
    const int w    = tid >> 6;
    const int lane = tid & 63;
    const int wm   = (w & 1) * 64;
    const int wn   = (w >> 1) * 64;
    const int fm   = lane & 15;
    const int fq   = lane >> 4;

    const int sr = tid >> 2;
    const int sc = (tid & 3) * 8;

    ffrag acc[4][4] = {};

    for (int k0 = 0; k0 < CIN; k0 += 32) {
        bfrag a0 = *(const bfrag*)&xbf[(row0 + sr) * CIN + k0 + sc];
        bfrag a1 = *(const bfrag*)&xbf[(row0 + sr + 64) * CIN + k0 + sc];
        bfrag b0 = *(const bfrag*)&WT[(col0 + sr) * CIN + k0 + sc];
        bfrag b1 = *(const bfrag*)&WT[(col0 + sr + 64) * CIN + k0 + sc];
        __syncthreads();
        *(bfrag*)&As[sr][sc]      = a0;
        *(bfrag*)&As[sr + 64][sc] = a1;
        *(bfrag*)&Bs[sr][sc]      = b0;
        *(bfrag*)&Bs[sr + 64][sc] = b1;
        __syncthreads();

        bfrag af[4], bfr[4];
#pragma unroll
        for (int g = 0; g < 4; ++g) {
            af[g]  = *(const bfrag*)&As[wm + g * 16 + fm][fq * 8];
            bfr[g] = *(const bfrag*)&Bs[wn + g * 16 + fm][fq * 8];
        }
#pragma unroll
        for (int mg = 0; mg < 4; ++mg)
#pragma unroll
            for (int ng = 0; ng < 4; ++ng)
                acc[mg][ng] = __builtin_amdgcn_mfma_f32_16x16x32_bf16(
                    af[mg], bfr[ng], acc[mg][ng], 0, 0, 0);
    }

#pragma unroll
    for (int mg = 0; mg < 4; ++mg)
#pragma unroll
        for (int ng = 0; ng < 4; ++ng) {
            const int rbase = row0 + wm + mg * 16 + fq * 4;
            const int c     = col0 + wn + ng * 16 + fm;
#pragma unroll
            for (int r = 0; r < 4; ++r)
                xtb[(rbase + r) * HC + c] = f2b(acc[mg][ng][r]);
        }
}

// ---------------------------------------------------------------------------
// Kernel 4: per-node attention scores, reading bf16 xtb (unchanged).
// ---------------------------------------------------------------------------
__global__ __launch_bounds__(256) void att_scores(const short* __restrict__ xtb,
                                                  const float* __restrict__ att_src,
                                                  const float* __restrict__ att_dst,
                                                  float* __restrict__ ssrc,
                                                  float* __restrict__ sdst) {
    const int n = blockIdx.x * 4 + (threadIdx.x >> 6);
    const int l = threadIdx.x & 63;

    bfrag xv = *(const bfrag*)&xtb[n * HC + l * 8];
    const float4* as = (const float4*)&att_src[l * 8];
    float4 a0 = as[0], a1 = as[1];
    const float4* ad = (const float4*)&att_dst[l * 8];
    float4 b0 = ad[0], b1 = ad[1];

    float xf[8];
#pragma unroll
    for (int k = 0; k < 8; ++k) xf[k] = b2f(xv[k]);

    float ps = xf[0] * a0.x + xf[1] * a0.y + xf[2] * a0.z + xf[3] * a0.w +
               xf[4] * a1.x + xf[5] * a1.y + xf[6] * a1.z + xf[7] * a1.w;
    float pd = xf[0] * b0.x + xf[1] * b0.y + xf[2] * b0.z + xf[3] * b0.w +
               xf[4] * b1.x + xf[5] * b1.y + xf[6] * b1.z + xf[7] * b1.w;

    ps += __shfl_xor(ps, 4); ps += __shfl_xor(ps, 2); ps += __shfl_xor(ps, 1);
    pd += __shfl_xor(pd, 4); pd += __shfl_xor(pd, 2); pd += __shfl_xor(pd, 1);

    if ((l & 7) == 0) {
        ssrc[n * NHEAD + (l >> 3)] = ps;
        sdst[n * NHEAD + (l >> 3)] = pd;
    }
}

// ---------------------------------------------------------------------------
// Kernel 5: merged-head aggregation (unchanged from round 7: bf16 gather,
// batch->XCD swizzle, jlds source-id stash for dependency-free phase 3).
// ---------------------------------------------------------------------------
__global__ __launch_bounds__(256) void aggregate(const short* __restrict__ xtb,
                                                 const float* __restrict__ ssrc,
                                                 const float* __restrict__ sdst,
                                                 const int* __restrict__ cnt,
                                                 const int* __restrict__ rowptr0,
                                                 const int* __restrict__ col,
                                                 const float* __restrict__ bias,
                                                 float* __restrict__ out) {
    __shared__ float wlds[4][NHEAD][68];
    __shared__ int   jlds[4][64];
    const int nb   = threadIdx.x >> 6;
    const int lane = threadIdx.x & 63;
    const int blk  = blockIdx.x;
    const int bidx = blk & 7;                                   // batch -> XCD
    const int i    = bidx * NNODE + (blk >> 3) * 4 + nb;
    const int n    = i & (NNODE - 1);
    const int deg  = cnt[n];
    const int start = bidx * NEDGE + rowptr0[n];
    const int h    = lane >> 3;
    const int sub  = lane & 7;
    float* wrow = &wlds[nb][0][0];
    int*   jrow = &jlds[nb][0];

    for (int t = lane; t < NHEAD * 68; t += 64) wrow[t] = 0.f;
    jrow[lane] = i;

    const float sdh = sdst[i * NHEAD + h];
    float selfv = ssrc[i * NHEAD + h] + sdh;
    selfv = selfv >= 0.f ? selfv : NEG_SLOPE * selfv;

    // pass A: logits -> LDS, source ids -> LDS, running max
    float m = selfv;
    for (int e = sub; e < deg; e += 8) {
        int j = col[start + e];
        float v = ssrc[j * NHEAD + h] + sdh;
        v = v >= 0.f ? v : NEG_SLOPE * v;
        if (e < 64) {
            wrow[h * 68 + e] = v;
            if (h == 0) jrow[e] = j;
        }
        m = fmaxf(m, v);
    }
    m = fmaxf(m, __shfl_xor(m, 4));
    m = fmaxf(m, __shfl_xor(m, 2));
    m = fmaxf(m, __shfl_xor(m, 1));

    // pass B: exp, sum; overwrite LDS with unnormalized weights
    float sp = 0.f;
    for (int e = sub; e < deg; e += 8) {
        float v;
        if (e < 64) {
            v = wrow[h * 68 + e];
        } else {
            int j = col[start + e];
            v = ssrc[j * NHEAD + h] + sdh;
            v = v >= 0.f ? v : NEG_SLOPE * v;
        }
        float w = __expf(v - m);
        if (e < 64) wrow[h * 68 + e] = w;
        sp += w;
    }
    sp += __shfl_xor(sp, 4); sp += __shfl_xor(sp, 2); sp += __shfl_xor(sp, 1);
    const float eself = __expf(selfv - m);
    const float inv = 1.f / (sp + eself + 1e-16f);

    const int c8 = lane * 8;
    float acc[8] = {};

    // self-loop
    {
        bfrag xv = *(const bfrag*)&xtb[i * HC + c8];
#pragma unroll
        for (int k = 0; k < 8; ++k) acc[k] += eself * b2f(xv[k]);
    }

    const int degc = min(deg, 64);
    const int degp = (degc + 7) & ~7;
    for (int e0 = 0; e0 < degp; e0 += 8) {
        float4 wA = *(const float4*)&wrow[h * 68 + e0];
        float4 wB = *(const float4*)&wrow[h * 68 + e0 + 4];
        int4 jA = *(const int4*)&jrow[e0];
        int4 jB = *(const int4*)&jrow[e0 + 4];
        bfrag x0 = *(const bfrag*)&xtb[jA.x * HC + c8];
        bfrag x1 = *(const bfrag*)&xtb[jA.y * HC + c8];
        bfrag x2 = *(const bfrag*)&xtb[jA.z * HC + c8];
        bfrag x3 = *(const bfrag*)&xtb[jA.w * HC + c8];
        bfrag x4 = *(const bfrag*)&xtb[jB.x * HC + c8];
        bfrag x5 = *(const bfrag*)&xtb[jB.y * HC + c8];
        bfrag x6 = *(const bfrag*)&xtb[jB.z * HC + c8];
        bfrag x7 = *(const bfrag*)&xtb[jB.w * HC + c8];
#pragma unroll
        for (int k = 0; k < 8; ++k) {
            acc[k] += wA.x * b2f(x0[k]) + wA.y * b2f(x1[k]) +
                      wA.z * b2f(x2[k]) + wA.w * b2f(x3[k]) +
                      wB.x * b2f(x4[k]) + wB.y * b2f(x5[k]) +
                      wB.z * b2f(x6[k]) + wB.w * b2f(x7[k]);
        }
    }
    // correctness fallback for deg > 64
    for (int e = 64; e < deg; ++e) {
        int j = col[start + e];
        float v = ssrc[j * NHEAD + h] + sdh;
        v = v >= 0.f ? v : NEG_SLOPE * v;
        float wv = __expf(v - m);
        bfrag xv = *(const bfrag*)&xtb[j * HC + c8];
#pragma unroll
        for (int k = 0; k < 8; ++k) acc[k] += wv * b2f(xv[k]);
    }

    const float4 b0 = *(const float4*)&bias[c8];
    const float4 b1 = *(const float4*)&bias[c8 + 4];
    float4 o0 = {acc[0] * inv + b0.x, acc[1] * inv + b0.y,
                 acc[2] * inv + b0.z, acc[3] * inv + b0.w};
    float4 o1 = {acc[4] * inv + b1.x, acc[5] * inv + b1.y,
                 acc[6] * inv + b1.z, acc[7] * inv + b1.w};
    *(float4*)&out[i * HC + c8]     = o0;
    *(float4*)&out[i * HC + c8 + 4] = o1;
}

// ---------------------------------------------------------------------------
extern "C" void kernel_launch(void* const* d_in, const int* in_sizes, int n_in,
                              void* d_out, int out_size, void* d_ws, size_t ws_size,
                              hipStream_t stream) {
    const float* x       = (const float*)d_in[0];
    const int*   ei      = (const int*)d_in[1];
    const float* W       = (const float*)d_in[2];
    const float* att_src = (const float*)d_in[3];
    const float* att_dst = (const float*)d_in[4];
    const float* bias    = (const float*)d_in[5];
    float* out = (float*)d_out;

    char* ws = (char*)d_ws;
    short* xtb      = (short*)(ws);                                // 16777216 B
    float* ssrc     = (float*)(ws + 16777216);                     // 524288 B
    float* sdst     = (float*)(ws + 17301504);                     // 524288 B
    int*   cnt      = (int*)(ws + 17825792);                       // 8192 B
    int*   rowptr0  = (int*)(ws + 17833984);                       // 8192 B
    int*   widx     = (int*)(ws + 17842176);                       // 65536 B
    int*   col      = (int*)(ws + 17907712);                       // 1048576 B
    short* xbf      = (short*)(ws + 18956288);                     // 8388608 B
    short* WT       = (short*)(ws + 27344896);                     // 262144 B
    int*   cnt_part = (int*)(ws + 27607040);                       // 262144 B
                                                                   // total 27869184 B
    prep_kernel<<<2176 + NHIST, 256, 0, stream>>>(x, W, ei, xbf, WT, cnt_part);
    scan_kernel<<<1, 256, 0, stream>>>(cnt_part, cnt, rowptr0, widx);
    gemm_scatter<<<1536, 256, 0, stream>>>(xbf, WT, xtb, ei, widx, col);
    att_scores<<<BN_TOT / 4, 256, 0, stream>>>(xtb, att_src, att_dst, ssrc, sdst);
    aggregate<<<BN_TOT / 4, 256, 0, stream>>>(xtb, ssrc, sdst, cnt, rowptr0, col, bias, out);
}